// Round 4
// baseline (141.422 us; speedup 1.0000x reference)
//
#include <hip/hip_runtime.h>
#include <hip/hip_cooperative_groups.h>

namespace cg = cooperative_groups;

#define HEADS 8
#define HD 64
#define NN 256
#define CC 512
#define SCALE 0.125f

typedef _Float16 half4v __attribute__((ext_vector_type(4)));
typedef _Float16 half8v __attribute__((ext_vector_type(8)));
typedef float f32x4 __attribute__((ext_vector_type(4)));

// Single cooperative kernel.
// Phase 1 (384 blocks): one 64x64 projection tile each (z = blk>>7 picks q/k/v).
// grid.sync with device fences (qh/kh/vT cross XCDs).
// Phase 2 (blocks 0..255): fused attention, 4 waves = 2 row-groups x 2 m-halves.
__global__ __launch_bounds__(256, 2) void fused_kernel(
    const float* __restrict__ q, const float* __restrict__ k,
    const float* __restrict__ v, const float* __restrict__ Wq,
    const float* __restrict__ Wk, const float* __restrict__ Wv,
    _Float16* __restrict__ qh, _Float16* __restrict__ kh,
    _Float16* __restrict__ vT, float* __restrict__ attn,
    float* __restrict__ x)
{
    __shared__ __align__(16) char smem[26624];

    const int t = threadIdx.x;
    const int lane = t & 63;
    const int blk = blockIdx.x;

    // ===================== Phase 1: QKV projection =====================
    {
        _Float16 (*Xs)[72] = (_Float16 (*)[72])smem;
        _Float16 (*Ws)[72] = (_Float16 (*)[72])(smem + 9216);
        const int w = t >> 6;
        const int wr = w >> 1, wc = w & 1;
        const int l15 = lane & 15, g = lane >> 4;
        const int sc = t & 7, sr = t >> 3;

        const int z = blk >> 7;
        const int rem = blk & 127;
        const int r0 = (rem >> 3) * 64;   // token tile
        const int c0 = (rem & 7) * 64;    // channel tile
        const float* __restrict__ X = (z == 0) ? q : (z == 1) ? k : v;
        const float* __restrict__ W = (z == 0) ? Wq : (z == 1) ? Wk : Wv;

        f32x4 acc[2][2] = {};

        for (int k0 = 0; k0 < CC; k0 += 64) {
            #pragma unroll
            for (int p = 0; p < 2; ++p) {
                int row = sr + p * 32;
                const float* gx = X + (r0 + row) * CC + k0 + sc * 8;
                const float* gw = W + (c0 + row) * CC + k0 + sc * 8;
                float4 x0 = *(const float4*)gx, x1 = *(const float4*)(gx + 4);
                float4 w0 = *(const float4*)gw, w1 = *(const float4*)(gw + 4);
                half8v hx, hw;
                hx[0] = (_Float16)x0.x; hx[1] = (_Float16)x0.y;
                hx[2] = (_Float16)x0.z; hx[3] = (_Float16)x0.w;
                hx[4] = (_Float16)x1.x; hx[5] = (_Float16)x1.y;
                hx[6] = (_Float16)x1.z; hx[7] = (_Float16)x1.w;
                hw[0] = (_Float16)w0.x; hw[1] = (_Float16)w0.y;
                hw[2] = (_Float16)w0.z; hw[3] = (_Float16)w0.w;
                hw[4] = (_Float16)w1.x; hw[5] = (_Float16)w1.y;
                hw[6] = (_Float16)w1.z; hw[7] = (_Float16)w1.w;
                *(half8v*)&Xs[row][sc * 8] = hx;
                *(half8v*)&Ws[row][sc * 8] = hw;
            }
            __syncthreads();
            #pragma unroll
            for (int kk = 0; kk < 2; ++kk) {
                half8v af[2], bf[2];
                #pragma unroll
                for (int mi = 0; mi < 2; ++mi)
                    af[mi] = *(const half8v*)((z == 2)
                        ? &Xs[wr * 32 + mi * 16 + l15][kk * 32 + g * 8]
                        : &Ws[wr * 32 + mi * 16 + l15][kk * 32 + g * 8]);
                #pragma unroll
                for (int ni = 0; ni < 2; ++ni)
                    bf[ni] = *(const half8v*)((z == 2)
                        ? &Ws[wc * 32 + ni * 16 + l15][kk * 32 + g * 8]
                        : &Xs[wc * 32 + ni * 16 + l15][kk * 32 + g * 8]);
                #pragma unroll
                for (int mi = 0; mi < 2; ++mi)
                    #pragma unroll
                    for (int ni = 0; ni < 2; ++ni)
                        acc[mi][ni] = __builtin_amdgcn_mfma_f32_16x16x32_f16(
                            af[mi], bf[ni], acc[mi][ni], 0, 0, 0);
            }
            __syncthreads();
        }

        #pragma unroll
        for (int mi = 0; mi < 2; ++mi) {
            #pragma unroll
            for (int ni = 0; ni < 2; ++ni) {
                f32x4 a = acc[mi][ni];
                half4v hv;
                hv[0] = (_Float16)a[0]; hv[1] = (_Float16)a[1];
                hv[2] = (_Float16)a[2]; hv[3] = (_Float16)a[3];
                if (z < 2) {
                    int ch  = c0 + wr * 32 + mi * 16 + g * 4;
                    int tok = r0 + wc * 32 + ni * 16 + l15;
                    int bb = tok >> 8, n = tok & 255, h = ch >> 6, d = ch & 63;
                    _Float16* dst = ((z == 0) ? qh : kh)
                                  + (((bb * HEADS + h) * NN + n) * HD + d);
                    *(half4v*)dst = hv;
                } else {
                    int tok = r0 + wr * 32 + mi * 16 + g * 4;
                    int ch  = c0 + wc * 32 + ni * 16 + l15;
                    int bb = tok >> 8, m = tok & 255, h = ch >> 6, d = ch & 63;
                    _Float16* dst = vT + (((bb * HEADS + h) * HD + d) * NN + m);
                    *(half4v*)dst = hv;
                }
            }
        }
    }

    // ===================== grid-wide barrier =====================
    __threadfence();          // release: push qh/kh/vT past per-XCD L2
    cg::this_grid().sync();
    __threadfence();          // acquire: invalidate before cross-XCD reads

    if (blk >= 256) return;

    // ===================== Phase 2: fused attention =====================
    const int bh = blk >> 3, bb = bh >> 3, h = bh & 7;
    const int n0 = (blk & 7) * 32;
    const int w = __builtin_amdgcn_readfirstlane(t >> 6);
    const int rg = w & 1, mh = w >> 1;     // row-group, m-half
    const int l15 = lane & 15, g = lane >> 4;
    const int n = n0 + rg * 16 + l15;      // this lane's q-row

    _Float16 (*Plds)[16][136] = (_Float16 (*)[16][136])smem;  // [wave][row][mcol]
    float* red  = (float*)(smem + 17408);  // [rg][mh][l15][{max,sum}]
    float* Olds = (float*)(smem + 17920);  // [rg][row][68]

    const _Float16* qb = qh + (bh * NN + n) * HD + g * 8;
    half8v bq0 = *(const half8v*)qb;
    half8v bq1 = *(const half8v*)(qb + 32);

    // S^T over this m-half: A = K rows, B = Q
    f32x4 acc[8] = {};
    const _Float16* kb = kh + (bh * NN + mh * 128 + l15) * HD + g * 8;
    #pragma unroll
    for (int nf = 0; nf < 8; ++nf) {
        half8v a0 = *(const half8v*)(kb + nf * 16 * HD);
        half8v a1 = *(const half8v*)(kb + nf * 16 * HD + 32);
        acc[nf] = __builtin_amdgcn_mfma_f32_16x16x32_f16(a0, bq0, acc[nf], 0, 0, 0);
        acc[nf] = __builtin_amdgcn_mfma_f32_16x16x32_f16(a1, bq1, acc[nf], 0, 0, 0);
    }

    // local softmax over m-half
    float mx = -3.0e38f;
    #pragma unroll
    for (int nf = 0; nf < 8; ++nf)
        #pragma unroll
        for (int r = 0; r < 4; ++r) mx = fmaxf(mx, acc[nf][r]);
    mx = fmaxf(mx, __shfl_xor(mx, 16, 64));
    mx = fmaxf(mx, __shfl_xor(mx, 32, 64));
    const float ml = mx * SCALE;

    float sloc = 0.f;
    #pragma unroll
    for (int nf = 0; nf < 8; ++nf)
        #pragma unroll
        for (int r = 0; r < 4; ++r) {
            float e = __expf(acc[nf][r] * SCALE - ml);
            acc[nf][r] = e;
            sloc += e;
        }
    sloc += __shfl_xor(sloc, 16, 64);
    sloc += __shfl_xor(sloc, 32, 64);

    // merge the two m-halves (per row): exchange (max, sum)
    if (g == 0) {
        red[((rg * 2 + mh) * 16 + l15) * 2 + 0] = ml;
        red[((rg * 2 + mh) * 16 + l15) * 2 + 1] = sloc;
    }
    __syncthreads();
    const float mo = red[((rg * 2 + (mh ^ 1)) * 16 + l15) * 2 + 0];
    const float so = red[((rg * 2 + (mh ^ 1)) * 16 + l15) * 2 + 1];
    const float M = fmaxf(ml, mo);
    const float fl = __expf(ml - M);
    const float pscale = fl / (sloc * fl + so * __expf(mo - M));

    // attn store (fp32) + P pack (fp16) for PV
    float* arow = attn + (bh * NN + n) * NN + mh * 128;
    #pragma unroll
    for (int nf = 0; nf < 8; ++nf) {
        float4 pv4;
        pv4.x = acc[nf][0] * pscale; pv4.y = acc[nf][1] * pscale;
        pv4.z = acc[nf][2] * pscale; pv4.w = acc[nf][3] * pscale;
        *(float4*)(arow + nf * 16 + g * 4) = pv4;
        half4v hv;
        hv[0] = (_Float16)pv4.x; hv[1] = (_Float16)pv4.y;
        hv[2] = (_Float16)pv4.z; hv[3] = (_Float16)pv4.w;
        *(half4v*)&Plds[w][l15][nf * 16 + g * 4] = hv;
    }
    asm volatile("s_waitcnt lgkmcnt(0)" ::: "memory");  // wave-local LDS order

    half8v pb[4];
    #pragma unroll
    for (int mt = 0; mt < 4; ++mt)
        pb[mt] = *(const half8v*)&Plds[w][l15][mt * 32 + g * 8];

    // partial O = P_half @ V_half  (A = vT rows d, B = P)
    f32x4 O[4] = {};
    #pragma unroll
    for (int df = 0; df < 4; ++df) {
        const _Float16* vb = vT + (bh * HD + df * 16 + l15) * NN + mh * 128 + g * 8;
        #pragma unroll
        for (int mt = 0; mt < 4; ++mt) {
            half8v av = *(const half8v*)(vb + mt * 32);
            O[df] = __builtin_amdgcn_mfma_f32_16x16x32_f16(av, pb[mt], O[df], 0, 0, 0);
        }
    }

    // combine the two m-half partials, store x
    if (mh == 1) {
        #pragma unroll
        for (int df = 0; df < 4; ++df)
            *(f32x4*)&Olds[(rg * 16 + l15) * 68 + df * 16 + g * 4] = O[df];
    }
    __syncthreads();
    if (mh == 0) {
        float* xb = x + (bb * NN + n) * CC + h * HD;
        #pragma unroll
        for (int df = 0; df < 4; ++df) {
            f32x4 o2 = *(const f32x4*)&Olds[(rg * 16 + l15) * 68 + df * 16 + g * 4];
            float4 st;
            st.x = O[df][0] + o2[0]; st.y = O[df][1] + o2[1];
            st.z = O[df][2] + o2[2]; st.w = O[df][3] + o2[3];
            *(float4*)(xb + df * 16 + g * 4) = st;
        }
    }
}

// ---------------------------------------------------------------------------
extern "C" void kernel_launch(void* const* d_in, const int* in_sizes, int n_in,
                              void* d_out, int out_size, void* d_ws, size_t ws_size,
                              hipStream_t stream) {
    const float* q  = (const float*)d_in[0];
    const float* k  = (const float*)d_in[1];
    const float* v  = (const float*)d_in[2];
    // d_in[3] relation_feature, d_in[7] W_r_conv, d_in[8] W_r_qk: dead in ref
    const float* Wq = (const float*)d_in[4];
    const float* Wk = (const float*)d_in[5];
    const float* Wv = (const float*)d_in[6];

    float* x    = (float*)d_out;                  // [4,256,512]
    float* attn = (float*)d_out + 4 * 256 * 512;  // [4,8,256,256]

    _Float16* qh = (_Float16*)d_ws;               // [32][256][64]
    _Float16* kh = qh + 32 * 256 * 64;            // [32][256][64]
    _Float16* vT = kh + 32 * 256 * 64;            // [32][64][256]

    void* args[] = {&q, &k, &v, &Wq, &Wk, &Wv, &qh, &kh, &vT, &attn, &x};
    hipLaunchCooperativeKernel((void*)fused_kernel, dim3(384), dim3(256),
                               args, 0, stream);
}

// Round 5
// 27.404 us; speedup vs baseline: 5.1606x; 5.1606x over previous
//
#include <hip/hip_runtime.h>

#define HEADS 8
#define HD 64
#define NN 256
#define CC 512
#define SCALE 0.125f

typedef _Float16 half4v __attribute__((ext_vector_type(4)));
typedef _Float16 half8v __attribute__((ext_vector_type(8)));
typedef float f32x4 __attribute__((ext_vector_type(4)));

static __device__ __forceinline__ half8v cvt8(float4 a, float4 b) {
    half8v h;
    h[0] = (_Float16)a.x; h[1] = (_Float16)a.y;
    h[2] = (_Float16)a.z; h[3] = (_Float16)a.w;
    h[4] = (_Float16)b.x; h[5] = (_Float16)b.y;
    h[6] = (_Float16)b.z; h[7] = (_Float16)b.w;
    return h;
}

// ---------------------------------------------------------------------------
// Kernel 1: QKV projection, fp16 MFMA, 64x64 tiles, register-prefetch pipeline.
//   z=0: qh[bh][n][d]   z=1: kh[bh][m][d]   z=2: vT[bh][d][m]
// ---------------------------------------------------------------------------
__global__ __launch_bounds__(256, 2) void proj_kernel(
    const float* __restrict__ q, const float* __restrict__ k,
    const float* __restrict__ v, const float* __restrict__ Wq,
    const float* __restrict__ Wk, const float* __restrict__ Wv,
    _Float16* __restrict__ qh, _Float16* __restrict__ kh,
    _Float16* __restrict__ vT)
{
    const int z = blockIdx.z;
    const float* __restrict__ X = (z == 0) ? q : (z == 1) ? k : v;
    const float* __restrict__ W = (z == 0) ? Wq : (z == 1) ? Wk : Wv;

    const int r0 = blockIdx.x * 64;   // token tile
    const int c0 = blockIdx.y * 64;   // channel tile

    __shared__ _Float16 Xs[64][72];
    __shared__ _Float16 Ws[64][72];

    const int t = threadIdx.x;
    const int lane = t & 63;
    const int w = t >> 6;
    const int wr = w >> 1, wc = w & 1;
    const int l15 = lane & 15, g = lane >> 4;
    const int sc = t & 7, sr = t >> 3;   // staging: 8 k-chunks x 32 rows

    const float* gx0 = X + (r0 + sr) * CC + sc * 8;
    const float* gx1 = X + (r0 + sr + 32) * CC + sc * 8;
    const float* gw0 = W + (c0 + sr) * CC + sc * 8;
    const float* gw1 = W + (c0 + sr + 32) * CC + sc * 8;

    // prefetch k0 = 0
    float4 xa0 = *(const float4*)gx0, xa1 = *(const float4*)(gx0 + 4);
    float4 xb0 = *(const float4*)gx1, xb1 = *(const float4*)(gx1 + 4);
    float4 wa0 = *(const float4*)gw0, wa1 = *(const float4*)(gw0 + 4);
    float4 wb0 = *(const float4*)gw1, wb1 = *(const float4*)(gw1 + 4);

    f32x4 acc[2][2] = {};

    for (int k0 = 0; k0 < CC; k0 += 64) {
        *(half8v*)&Xs[sr][sc * 8]      = cvt8(xa0, xa1);
        *(half8v*)&Xs[sr + 32][sc * 8] = cvt8(xb0, xb1);
        *(half8v*)&Ws[sr][sc * 8]      = cvt8(wa0, wa1);
        *(half8v*)&Ws[sr + 32][sc * 8] = cvt8(wb0, wb1);
        __syncthreads();

        if (k0 + 64 < CC) {   // issue next-tile loads; latency hides under MFMA
            xa0 = *(const float4*)(gx0 + k0 + 64); xa1 = *(const float4*)(gx0 + k0 + 68);
            xb0 = *(const float4*)(gx1 + k0 + 64); xb1 = *(const float4*)(gx1 + k0 + 68);
            wa0 = *(const float4*)(gw0 + k0 + 64); wa1 = *(const float4*)(gw0 + k0 + 68);
            wb0 = *(const float4*)(gw1 + k0 + 64); wb1 = *(const float4*)(gw1 + k0 + 68);
        }

        #pragma unroll
        for (int kk = 0; kk < 2; ++kk) {
            half8v af[2], bf[2];
            #pragma unroll
            for (int mi = 0; mi < 2; ++mi)
                af[mi] = *(const half8v*)((z == 2)
                    ? &Xs[wr * 32 + mi * 16 + l15][kk * 32 + g * 8]
                    : &Ws[wr * 32 + mi * 16 + l15][kk * 32 + g * 8]);
            #pragma unroll
            for (int ni = 0; ni < 2; ++ni)
                bf[ni] = *(const half8v*)((z == 2)
                    ? &Ws[wc * 32 + ni * 16 + l15][kk * 32 + g * 8]
                    : &Xs[wc * 32 + ni * 16 + l15][kk * 32 + g * 8]);
            #pragma unroll
            for (int mi = 0; mi < 2; ++mi)
                #pragma unroll
                for (int ni = 0; ni < 2; ++ni)
                    acc[mi][ni] = __builtin_amdgcn_mfma_f32_16x16x32_f16(
                        af[mi], bf[ni], acc[mi][ni], 0, 0, 0);
        }
        __syncthreads();
    }

    #pragma unroll
    for (int mi = 0; mi < 2; ++mi) {
        #pragma unroll
        for (int ni = 0; ni < 2; ++ni) {
            f32x4 a = acc[mi][ni];
            half4v hv;
            hv[0] = (_Float16)a[0]; hv[1] = (_Float16)a[1];
            hv[2] = (_Float16)a[2]; hv[3] = (_Float16)a[3];
            if (z < 2) {
                int ch  = c0 + wr * 32 + mi * 16 + g * 4;
                int tok = r0 + wc * 32 + ni * 16 + l15;
                int bb = tok >> 8, n = tok & 255, h = ch >> 6, d = ch & 63;
                _Float16* dst = ((z == 0) ? qh : kh)
                              + (((bb * HEADS + h) * NN + n) * HD + d);
                *(half4v*)dst = hv;
            } else {
                int tok = r0 + wr * 32 + mi * 16 + g * 4;
                int ch  = c0 + wc * 32 + ni * 16 + l15;
                int bb = tok >> 8, m = tok & 255, h = ch >> 6, d = ch & 63;
                _Float16* dst = vT + (((bb * HEADS + h) * HD + d) * NN + m);
                *(half4v*)dst = hv;
            }
        }
    }
}

// ---------------------------------------------------------------------------
// Kernel 2: fused attention. Grid (16, 32): 16 rows/block, 4 waves = m-quarters.
// 512 blocks x 256 thr = 2048 waves = 2 waves/SIMD.
// Swapped QK (S^T = K Q^T): softmax over m is in-lane(16) + shfl(16,32),
// merged across the 4 m-quarters via a tiny LDS exchange.
// ---------------------------------------------------------------------------
__global__ __launch_bounds__(256, 2) void attn_kernel(
    const _Float16* __restrict__ qh, const _Float16* __restrict__ kh,
    const _Float16* __restrict__ vT, float* __restrict__ attn,
    float* __restrict__ x)
{
    __shared__ _Float16 Plds[4][16][136];   // [wave][n-row][m-col], padded
    __shared__ float red[4][16][2];         // per-quarter {max, sum}
    __shared__ float Olds[4][16][68];       // per-quarter O partials

    const int t = threadIdx.x, lane = t & 63;
    const int w = __builtin_amdgcn_readfirstlane(t >> 6);  // m-quarter
    const int l15 = lane & 15, g = lane >> 4;
    const int bh = blockIdx.y, bb = bh >> 3, h = bh & 7;
    const int n0 = blockIdx.x * 16;
    const int n = n0 + l15;                 // this lane's q-row

    // Q as B-operand (all waves load the same rows)
    const _Float16* qb = qh + (bh * NN + n) * HD + g * 8;
    half8v bq0 = *(const half8v*)qb;
    half8v bq1 = *(const half8v*)(qb + 32);

    // S^T over this m-quarter: A = K rows
    f32x4 acc[4] = {};
    const _Float16* kb = kh + (bh * NN + w * 64 + l15) * HD + g * 8;
    #pragma unroll
    for (int nf = 0; nf < 4; ++nf) {
        half8v a0 = *(const half8v*)(kb + nf * 16 * HD);
        half8v a1 = *(const half8v*)(kb + nf * 16 * HD + 32);
        acc[nf] = __builtin_amdgcn_mfma_f32_16x16x32_f16(a0, bq0, acc[nf], 0, 0, 0);
        acc[nf] = __builtin_amdgcn_mfma_f32_16x16x32_f16(a1, bq1, acc[nf], 0, 0, 0);
    }

    // local softmax stats over the quarter
    float mx = -3.0e38f;
    #pragma unroll
    for (int nf = 0; nf < 4; ++nf)
        #pragma unroll
        for (int r = 0; r < 4; ++r) mx = fmaxf(mx, acc[nf][r]);
    mx = fmaxf(mx, __shfl_xor(mx, 16, 64));
    mx = fmaxf(mx, __shfl_xor(mx, 32, 64));
    const float ml = mx * SCALE;

    float sloc = 0.f;
    #pragma unroll
    for (int nf = 0; nf < 4; ++nf)
        #pragma unroll
        for (int r = 0; r < 4; ++r) {
            float e = __expf(acc[nf][r] * SCALE - ml);
            acc[nf][r] = e;
            sloc += e;
        }
    sloc += __shfl_xor(sloc, 16, 64);
    sloc += __shfl_xor(sloc, 32, 64);

    // merge the 4 quarters per row
    if (g == 0) {
        red[w][l15][0] = ml;
        red[w][l15][1] = sloc;
    }
    __syncthreads();
    float M = -3.0e38f;
    #pragma unroll
    for (int ww = 0; ww < 4; ++ww) M = fmaxf(M, red[ww][l15][0]);
    float S = 0.f;
    #pragma unroll
    for (int ww = 0; ww < 4; ++ww)
        S += red[ww][l15][1] * __expf(red[ww][l15][0] - M);
    const float pscale = __expf(ml - M) / S;

    // attn store (fp32) + P pack (fp16) for PV
    float* arow = attn + (bh * NN + n) * NN + w * 64;
    #pragma unroll
    for (int nf = 0; nf < 4; ++nf) {
        float4 pv4;
        pv4.x = acc[nf][0] * pscale; pv4.y = acc[nf][1] * pscale;
        pv4.z = acc[nf][2] * pscale; pv4.w = acc[nf][3] * pscale;
        *(float4*)(arow + nf * 16 + g * 4) = pv4;
        half4v hv;
        hv[0] = (_Float16)pv4.x; hv[1] = (_Float16)pv4.y;
        hv[2] = (_Float16)pv4.z; hv[3] = (_Float16)pv4.w;
        *(half4v*)&Plds[w][l15][nf * 16 + g * 4] = hv;
    }
    asm volatile("s_waitcnt lgkmcnt(0)" ::: "memory");  // wave-local LDS order

    half8v pb[2];
    #pragma unroll
    for (int mt = 0; mt < 2; ++mt)
        pb[mt] = *(const half8v*)&Plds[w][l15][mt * 32 + g * 8];

    // partial O = P_quarter @ V_quarter  (A = vT rows d, B = P)
    f32x4 O[4] = {};
    #pragma unroll
    for (int df = 0; df < 4; ++df) {
        const _Float16* vb = vT + (bh * HD + df * 16 + l15) * NN + w * 64 + g * 8;
        #pragma unroll
        for (int mt = 0; mt < 2; ++mt) {
            half8v av = *(const half8v*)(vb + mt * 32);
            O[df] = __builtin_amdgcn_mfma_f32_16x16x32_f16(av, pb[mt], O[df], 0, 0, 0);
        }
    }

    // combine the 4 partials: wave w writes, then owns d-quarter w of output
    #pragma unroll
    for (int df = 0; df < 4; ++df)
        *(f32x4*)&Olds[w][l15][df * 16 + g * 4] = O[df];
    __syncthreads();

    f32x4 o = *(const f32x4*)&Olds[0][l15][w * 16 + g * 4];
    #pragma unroll
    for (int src = 1; src < 4; ++src) {
        f32x4 p = *(const f32x4*)&Olds[src][l15][w * 16 + g * 4];
        o[0] += p[0]; o[1] += p[1]; o[2] += p[2]; o[3] += p[3];
    }
    float4 st; st.x = o[0]; st.y = o[1]; st.z = o[2]; st.w = o[3];
    *(float4*)(x + (bb * NN + n) * CC + h * HD + w * 16 + g * 4) = st;
}

// ---------------------------------------------------------------------------
extern "C" void kernel_launch(void* const* d_in, const int* in_sizes, int n_in,
                              void* d_out, int out_size, void* d_ws, size_t ws_size,
                              hipStream_t stream) {
    const float* q  = (const float*)d_in[0];
    const float* k  = (const float*)d_in[1];
    const float* v  = (const float*)d_in[2];
    // d_in[3] relation_feature, d_in[7] W_r_conv, d_in[8] W_r_qk: dead in ref
    const float* Wq = (const float*)d_in[4];
    const float* Wk = (const float*)d_in[5];
    const float* Wv = (const float*)d_in[6];

    float* x    = (float*)d_out;                  // [4,256,512]
    float* attn = (float*)d_out + 4 * 256 * 512;  // [4,8,256,256]

    _Float16* qh = (_Float16*)d_ws;               // [32][256][64]
    _Float16* kh = qh + 32 * 256 * 64;            // [32][256][64]
    _Float16* vT = kh + 32 * 256 * 64;            // [32][64][256]

    proj_kernel<<<dim3(16, 8, 3), 256, 0, stream>>>(q, k, v, Wq, Wk, Wv, qh, kh, vT);
    attn_kernel<<<dim3(16, 32), 256, 0, stream>>>(qh, kh, vT, attn, x);
}